// Round 12
// baseline (613.552 us; speedup 1.0000x reference)
//
#include <hip/hip_runtime.h>
#include <math.h>

typedef _Float16 half8 __attribute__((ext_vector_type(8)));
typedef _Float16 half4v __attribute__((ext_vector_type(4)));
typedef _Float16 half2v __attribute__((ext_vector_type(2)));
typedef float floatx16 __attribute__((ext_vector_type(16)));
typedef float floatx4 __attribute__((ext_vector_type(4)));

#define TT 20
#define NB 64      // batch per step
#define LL 90
#define DD 64
#define RR 5760    // L*D
#define HH 1024
#define NG 4096    // 4*H
#define KT 6784    // RR + HH
#define CH0 90     // chunks in K-part0 (5760/64)
#define CHT 106    // total 64-half chunks (6784/64)

__device__ __forceinline__ float sigm(float x) { return 1.f / (1.f + expf(-x)); }

// ---------------- fp32 -> fp16 convert (both weight arrays, one launch) ----------------
__global__ __launch_bounds__(256) void k_conv2(const float* __restrict__ s1, _Float16* __restrict__ d1, int n1,
                                               const float* __restrict__ s2, _Float16* __restrict__ d2, int n2) {
    int i = (blockIdx.x * 256 + threadIdx.x) * 4;
    const float* s; _Float16* d;
    if (i < n1) { s = s1 + i; d = d1 + i; }
    else if ((i -= n1) < n2) { s = s2 + i; d = d2 + i; }
    else return;
    const float4 v = *(const float4*)s;
    half4v o;
    o[0] = (_Float16)v.x; o[1] = (_Float16)v.y;
    o[2] = (_Float16)v.z; o[3] = (_Float16)v.w;
    *(half4v*)d = o;
}

// ---------------- init h0, c0 ----------------
__global__ __launch_bounds__(256) void k_init(const float* __restrict__ feat,
        const float* __restrict__ iWh_w, const float* __restrict__ iWh_b,
        const float* __restrict__ iWc_w, const float* __restrict__ iWc_b,
        float* __restrict__ h, float* __restrict__ c, _Float16* __restrict__ h16) {
    __shared__ float f0p[4][DD];
    __shared__ float f0[DD];
    const int b = blockIdx.x, tid = threadIdx.x;
    const int dd = tid & 63, lg = tid >> 6;
    const float* frow = feat + (size_t)(b * TT) * RR;   // t = 0
    float p = 0;
    for (int l = lg; l < LL; l += 4) p += frow[l * DD + dd];
    f0p[lg][dd] = p;
    __syncthreads();
    if (tid < DD) f0[tid] = (f0p[0][tid] + f0p[1][tid] + f0p[2][tid] + f0p[3][tid]) * (1.0f / LL);
    __syncthreads();
    for (int o = tid; o < HH; o += 256) {
        float ah = iWh_b[o], ac = iWc_b[o];
        for (int d0 = 0; d0 < DD; d0 += 4) {
            const float4 wh = *(const float4*)(iWh_w + (size_t)o * DD + d0);
            const float4 wc = *(const float4*)(iWc_w + (size_t)o * DD + d0);
            ah += f0[d0] * wh.x + f0[d0 + 1] * wh.y + f0[d0 + 2] * wh.z + f0[d0 + 3] * wh.w;
            ac += f0[d0] * wc.x + f0[d0 + 1] * wc.y + f0[d0 + 2] * wc.z + f0[d0 + 3] * wc.w;
        }
        const float hv = tanhf(ah), cv = tanhf(ac);
        h[b * HH + o] = hv; c[b * HH + o] = cv;
        h16[b * HH + o] = (_Float16)hv;
    }
}

// ===== fused LSTM cell (step tattn-1, if do_cell) + attention for step tattn
//       + head partials; final call (tattn==TT) assembles out. =====
// 64 blocks (one per batch b) x 512 threads. xproj computed in-block via MFMA.
__global__ __launch_bounds__(512) void k_step(int tattn, int do_cell,
        const float* __restrict__ gpart, const float* __restrict__ b_ih,
        const float* __restrict__ b_hh, float* __restrict__ cbuf,
        _Float16* __restrict__ h16, const float* __restrict__ h0buf,
        const float* __restrict__ feat, const _Float16* __restrict__ WxTg,
        const float* __restrict__ Wh, const float* __restrict__ v,
        _Float16* __restrict__ V16, const _Float16* __restrict__ Wyu,
        float* __restrict__ vpart, float* __restrict__ hpart,
        const float* __restrict__ cst, float* __restrict__ out) {
    __shared__ float sf[RR];               // feature row fp32 (23 KB)
    __shared__ _Float16 x16[96 * DD];      // feature row fp16, rows 90..95 zero (12 KB)
    __shared__ _Float16 wxT[DD * DD];      // WxT[a][d] fp16 (8 KB)
    __shared__ float sh[HH];
    __shared__ float hWhp[8][DD];
    __shared__ float hWh[DD];
    __shared__ float sv[DD];
    __shared__ float se[128];
    __shared__ float red[128];
    __shared__ float salpha[LL];
    __shared__ float hdr[8][6];
    __shared__ float hloc[3];
    const int b = blockIdx.x, tid = threadIdx.x;
    const int t = tattn;
    if (tid < DD) sv[tid] = v[tid];
    float hp0 = 0.f, hp1 = 0.f, hp2 = 0.f;
    float vp0 = 0.f, vp1 = 0.f, vp2 = 0.f;

    if (t < TT) {   // stage feature row (fp32 + fp16) and WxT
        const float* frow = feat + ((size_t)b * TT + t) * RR;
        for (int e = tid * 4; e < RR; e += 2048) {
            const float4 u = *(const float4*)(frow + e);
            *(float4*)(sf + e) = u;
            half4v o;
            o[0] = (_Float16)u.x; o[1] = (_Float16)u.y;
            o[2] = (_Float16)u.z; o[3] = (_Float16)u.w;
            *(half4v*)(x16 + e) = o;
        }
        if (tid < 48) *(half8*)(x16 + RR + tid * 8) = half8{0,0,0,0,0,0,0,0};
        *(half8*)(wxT + tid * 8) = *(const half8*)(WxTg + tid * 8);
    }

    if (do_cell) {
        // ----- cell for step t-1: 2 hidden units per thread, 4 split-K partials -----
        const int j0 = tid * 2;
        float ag[4][2];
#pragma unroll
        for (int g = 0; g < 4; ++g) { ag[g][0] = 0.f; ag[g][1] = 0.f; }
#pragma unroll
        for (int sp = 0; sp < 4; ++sp) {
            const float* P = gpart + ((size_t)sp * NB + b) * NG;
#pragma unroll
            for (int g = 0; g < 4; ++g) {
                const float2 pv = *(const float2*)(P + g * HH + j0);
                ag[g][0] += pv.x; ag[g][1] += pv.y;
            }
        }
#pragma unroll
        for (int g = 0; g < 4; ++g) {
            const float2 bi = *(const float2*)(b_ih + g * HH + j0);
            const float2 bh = *(const float2*)(b_hh + g * HH + j0);
            ag[g][0] += bi.x + bh.x; ag[g][1] += bi.y + bh.y;
        }
        const float2 cold = *(const float2*)(cbuf + (size_t)b * HH + j0);
        float co[2] = { cold.x, cold.y };
        float2 cnew; half2v hh2;
#pragma unroll
        for (int q = 0; q < 2; ++q) {
            const float cv = sigm(ag[1][q]) * co[q] + sigm(ag[0][q]) * tanhf(ag[2][q]);
            const float hv = sigm(ag[3][q]) * tanhf(cv);
            ((float*)&cnew)[q] = cv;
            hh2[q] = (_Float16)hv;
            sh[j0 + q] = hv;
        }
        *(float2*)(cbuf + (size_t)b * HH + j0) = cnew;
        *(half2v*)(h16 + (size_t)b * HH + j0) = hh2;
        // head partial: h(t-1) . Wyu[:, RR+j0..j0+1]  (rounded fp16 h, as in V path)
        const float h0f = (float)hh2[0], h1f = (float)hh2[1];
        hp0 = h0f * (float)Wyu[0 * KT + RR + j0] + h1f * (float)Wyu[0 * KT + RR + j0 + 1];
        hp1 = h0f * (float)Wyu[1 * KT + RR + j0] + h1f * (float)Wyu[1 * KT + RR + j0 + 1];
        hp2 = h0f * (float)Wyu[2 * KT + RR + j0] + h1f * (float)Wyu[2 * KT + RR + j0 + 1];
    } else {
        for (int e = tid; e < HH; e += 512) sh[e] = h0buf[(size_t)b * HH + e];
    }
    __syncthreads();

    if (t < TT) {   // attention + visual for step t (uniform branch)
        // ----- hWh = h @ Wh : 8-way K-split, coalesced 256B wave loads (fp32 Wh) -----
        { const int a = tid & 63, q = tid >> 6;           // q in 0..7
          const float* Wq = Wh + (size_t)(q * 128) * DD + a;
          const float* shq = sh + q * 128;
          float p0 = 0.f, p1 = 0.f;
#pragma unroll 8
          for (int k = 0; k < 128; k += 2) {
              p0 += shq[k] * Wq[(size_t)k * DD];
              p1 += shq[k + 1] * Wq[(size_t)(k + 1) * DD];
          }
          hWhp[q][a] = p0 + p1; }
        __syncthreads();
        if (tid < DD) {
            float s = 0.f;
#pragma unroll
            for (int q = 0; q < 8; ++q) s += hWhp[q][tid];
            hWh[tid] = s;
        }
        if (tid < 128) se[tid] = -1e30f;
        __syncthreads();

        // ----- e via MFMA: waves 0..5, l-tile = w*16 -----
        { const int w = tid >> 6, ln = tid & 63;
          if (w < 6) {
              const int l0 = w * 16, c = ln & 15, g = ln >> 4;
              float es[4] = {0.f, 0.f, 0.f, 0.f};
#pragma unroll
              for (int at = 0; at < 4; ++at) {
                  floatx4 acc = {0.f, 0.f, 0.f, 0.f};
#pragma unroll
                  for (int kk = 0; kk < 2; ++kk) {
                      const half8 af = *(const half8*)(x16 + (l0 + c) * DD + g * 8 + kk * 32);
                      const half8 bf = *(const half8*)(wxT + (at * 16 + c) * DD + g * 8 + kk * 32);
                      acc = __builtin_amdgcn_mfma_f32_16x16x32_f16(af, bf, acc, 0, 0, 0);
                  }
#pragma unroll
                  for (int q = 0; q < 4; ++q) {
                      const int aa = at * 16 + c;
                      es[q] += tanhf(acc[q] + hWh[aa]) * sv[aa];
                  }
              }
#pragma unroll
              for (int q = 0; q < 4; ++q) {
                  es[q] += __shfl_xor(es[q], 1, 64);
                  es[q] += __shfl_xor(es[q], 2, 64);
                  es[q] += __shfl_xor(es[q], 4, 64);
                  es[q] += __shfl_xor(es[q], 8, 64);
              }
              if (c == 0) {
#pragma unroll
                  for (int q = 0; q < 4; ++q) {
                      const int l = l0 + g * 4 + q;
                      if (l < LL) se[l] = es[q];
                  }
              }
          } }
        __syncthreads();

        // ----- softmax over se[0..89] -----
        if (tid < 128) red[tid] = se[tid];
        __syncthreads();
        for (int s = 64; s; s >>= 1) { if (tid < s) red[tid] = fmaxf(red[tid], red[tid + s]); __syncthreads(); }
        const float mx = red[0];
        __syncthreads();
        float ex = 0.f;
        if (tid < LL) { ex = expf(se[tid] - mx); salpha[tid] = ex; }
        if (tid < 128) red[tid] = ex;
        __syncthreads();
        for (int s = 64; s; s >>= 1) { if (tid < s) red[tid] += red[tid + s]; __syncthreads(); }
        const float inv = 1.f / red[0];
        __syncthreads();
        if (tid < LL) salpha[tid] *= inv;
        __syncthreads();

        // ----- visual write + head partial V . Wyu[:, :RR] -----
        _Float16* vout = V16 + ((size_t)t * NB + b) * RR;
        for (int e = tid * 4; e < RR; e += 2048) {
            const float4 u4 = *(const float4*)(sf + e);
            const float al = salpha[e >> 6];
            half4v o;
            o[0] = (_Float16)(u4.x * al); o[1] = (_Float16)(u4.y * al);
            o[2] = (_Float16)(u4.z * al); o[3] = (_Float16)(u4.w * al);
            *(half4v*)(vout + e) = o;
            const half4v w0 = *(const half4v*)(Wyu + e);
            const half4v w1 = *(const half4v*)(Wyu + KT + e);
            const half4v w2 = *(const half4v*)(Wyu + 2 * KT + e);
#pragma unroll
            for (int u = 0; u < 4; ++u) {
                const float xv = (float)o[u];
                vp0 += xv * (float)w0[u]; vp1 += xv * (float)w1[u]; vp2 += xv * (float)w2[u];
            }
        }
    }

    // ----- reduce 6 head partials across 512 threads -----
    for (int o = 32; o; o >>= 1) {
        hp0 += __shfl_down(hp0, o, 64); hp1 += __shfl_down(hp1, o, 64); hp2 += __shfl_down(hp2, o, 64);
        vp0 += __shfl_down(vp0, o, 64); vp1 += __shfl_down(vp1, o, 64); vp2 += __shfl_down(vp2, o, 64);
    }
    if ((tid & 63) == 0) {
        const int wv = tid >> 6;
        hdr[wv][0] = hp0; hdr[wv][1] = hp1; hdr[wv][2] = hp2;
        hdr[wv][3] = vp0; hdr[wv][4] = vp1; hdr[wv][5] = vp2;
    }
    __syncthreads();
    if (tid < 6) {
        float s = 0.f;
#pragma unroll
        for (int wv = 0; wv < 8; ++wv) s += hdr[wv][tid];
        if (tid < 3) {
            if (do_cell) { hpart[((size_t)(t - 1) * NB + b) * 3 + tid] = s; hloc[tid] = s; }
        } else {
            if (t < TT) vpart[((size_t)t * NB + b) * 3 + (tid - 3)] = s;
        }
    }
    __syncthreads();
    if (t == TT) {   // final call: assemble out rows for batch b
        for (int i = tid; i < TT * 3; i += 512) {
            const int ts = i / 3, j = i - ts * 3;
            const float hp = (ts == TT - 1) ? hloc[j] : hpart[((size_t)ts * NB + b) * 3 + j];
            out[((size_t)b * TT + ts) * 3 + j] = vpart[((size_t)ts * NB + b) * 3 + j] + hp + cst[j];
        }
    }
}

// ================= tiled GEMM machinery (gates) =================
__device__ __forceinline__ void stage_tile(const char* src, size_t stride, char* lds, int ln) {
    const char* g = src + (size_t)(ln >> 3) * stride + (((ln & 7) ^ (ln >> 3)) << 4);
#pragma unroll
    for (int i = 0; i < 8; ++i)
        __builtin_amdgcn_global_load_lds(
            (const __attribute__((address_space(1))) void*)(g + (size_t)(i * 8) * stride),
            (__attribute__((address_space(3))) void*)(lds + i * 1024), 16, 0, 0);
}

struct Src2 { const char* p0; size_t s0; const char* p1; size_t s1; };

__device__ __forceinline__ const char* chunk_ptr(const Src2& s, int c, size_t& stride) {
    if (c < CH0) { stride = s.s0; return s.p0 + (size_t)c * 128; }
    stride = s.s1; return s.p1 + (size_t)(c - CH0) * 128;
}

template<int NT, int SB>
__global__ __launch_bounds__(128) void k_gemm(
        const _Float16* __restrict__ A0, const _Float16* __restrict__ A1,
        const _Float16* __restrict__ B0, const _Float16* __restrict__ B1,
        float* __restrict__ C, int ldc, size_t part_elems) {
    __shared__ char smem[65536];
    const int bid = blockIdx.x;
    const int kb = bid % SB;
    const int nt = (bid / SB) % NT;
    const int mt = bid / (SB * NT);
    const int tid = threadIdx.x, w = tid >> 6, ln = tid & 63;
    char* wlds = smem + w * 32768;

    const int arow = mt * 64, brow = nt * 64;
    Src2 As = { (const char*)(A0 + (size_t)arow * RR), (size_t)RR * 2,
                (const char*)(A1 + (size_t)arow * HH), (size_t)HH * 2 };
    Src2 Bs = { (const char*)(B0 + (size_t)brow * RR), (size_t)RR * 2,
                (const char*)(B1 + (size_t)brow * HH), (size_t)HH * 2 };

    floatx16 acc00, acc01, acc10, acc11;
#pragma unroll
    for (int i = 0; i < 16; ++i) { acc00[i] = 0.f; acc01[i] = 0.f; acc10[i] = 0.f; acc11[i] = 0.f; }

    const int start = kb * 2 + w;
    const int STRIDE = SB * 2;
    const int r = ln & 31;
    const int xsw = (r & 7) << 4;
    const int fo = (ln >> 5) * 16;
    const int rbyte = r * 128;

    int c = start, bsel = 0;
    { size_t st; const char* p = chunk_ptr(As, c, st); stage_tile(p, st, wlds, ln);
      p = chunk_ptr(Bs, c, st); stage_tile(p, st, wlds + 8192, ln); }
    while (true) {
        const int cn = c + STRIDE;
        if (cn < CHT) {
            char* nl = wlds + ((bsel ^ 1) << 14);
            size_t st; const char* p = chunk_ptr(As, cn, st); stage_tile(p, st, nl, ln);
            p = chunk_ptr(Bs, cn, st); stage_tile(p, st, nl + 8192, ln);
            asm volatile("s_waitcnt vmcnt(16)" ::: "memory");
        } else {
            asm volatile("s_waitcnt vmcnt(0)" ::: "memory");
        }
        __builtin_amdgcn_sched_barrier(0);
        const char* LA = wlds + (bsel << 14);
        const char* LB = LA + 8192;
#pragma unroll
        for (int kk = 0; kk < 4; ++kk) {
            const int o = ((kk * 32 + fo) ^ xsw);
            const half8 a0 = *(const half8*)(LA + rbyte + o);
            const half8 a1 = *(const half8*)(LA + 4096 + rbyte + o);
            const half8 b0 = *(const half8*)(LB + rbyte + o);
            const half8 b1 = *(const half8*)(LB + 4096 + rbyte + o);
            acc00 = __builtin_amdgcn_mfma_f32_32x32x16_f16(a0, b0, acc00, 0, 0, 0);
            acc01 = __builtin_amdgcn_mfma_f32_32x32x16_f16(a0, b1, acc01, 0, 0, 0);
            acc10 = __builtin_amdgcn_mfma_f32_32x32x16_f16(a1, b0, acc10, 0, 0, 0);
            acc11 = __builtin_amdgcn_mfma_f32_32x32x16_f16(a1, b1, acc11, 0, 0, 0);
        }
        if (cn >= CHT) break;
        c = cn; bsel ^= 1;
    }
    __syncthreads();
    float* Rg = (float*)(smem + w * 16384);
    const int rbase = 4 * (ln >> 5), lr = ln & 31;
#pragma unroll
    for (int q = 0; q < 16; ++q) {
        const int row = rbase + (q & 3) + 8 * (q >> 2);
        Rg[row * 64 + lr]             = acc00[q];
        Rg[row * 64 + 32 + lr]        = acc01[q];
        Rg[(row + 32) * 64 + lr]      = acc10[q];
        Rg[(row + 32) * 64 + 32 + lr] = acc11[q];
    }
    __syncthreads();
    const float* R0 = (const float*)smem;
    const float* R1 = (const float*)(smem + 16384);
    float* Cout = C + (size_t)kb * part_elems;
    for (int e = tid * 4; e < 4096; e += 512) {
        const float4 u = *(const float4*)(R0 + e);
        const float4 v2 = *(const float4*)(R1 + e);
        float4 s2; s2.x = u.x + v2.x; s2.y = u.y + v2.y; s2.z = u.z + v2.z; s2.w = u.w + v2.w;
        const int row = e >> 6, col = e & 63;
        *(float4*)(Cout + (size_t)(arow + row) * ldc + brow + col) = s2;
    }
}

// ===== Wu-fused head weights: Wyu16[j] = Wu @ [Wy | Whw], cst[j]; + Wx transpose =====
__global__ __launch_bounds__(256) void k_wfuse(const float* __restrict__ Wy,
        const float* __restrict__ Whw, const float* __restrict__ Wu,
        const float* __restrict__ Whb, const float* __restrict__ Wub,
        _Float16* __restrict__ Wyu16, float* __restrict__ cst,
        const float* __restrict__ Wx, _Float16* __restrict__ WxT) {
    const int tid = threadIdx.x;
    if (blockIdx.x == CHT + 1) {   // WxT[a][d] = Wx[d][a] fp16
        const int a = tid >> 2, k0 = (tid & 3) * 16;
#pragma unroll
        for (int j = 0; j < 16; ++j)
            WxT[(size_t)a * DD + k0 + j] = (_Float16)Wx[(size_t)(k0 + j) * DD + a];
        return;
    }
    __shared__ float sWu[3 * HH];
    __shared__ float part[4][3][64];
    for (int e = tid * 4; e < 3 * HH; e += 1024)
        *(float4*)(sWu + e) = *(const float4*)(Wu + e);
    __syncthreads();
    if (blockIdx.x == CHT) {   // cst block
        float a0 = 0, a1 = 0, a2 = 0;
        for (int m = tid; m < HH; m += 256) {
            const float wb = Whb[m];
            a0 += sWu[m] * wb; a1 += sWu[HH + m] * wb; a2 += sWu[2 * HH + m] * wb;
        }
        __shared__ float rp[3][256];
        rp[0][tid] = a0; rp[1][tid] = a1; rp[2][tid] = a2;
        __syncthreads();
        for (int s = 128; s; s >>= 1) {
            if (tid < s) { rp[0][tid] += rp[0][tid + s]; rp[1][tid] += rp[1][tid + s]; rp[2][tid] += rp[2][tid + s]; }
            __syncthreads();
        }
        if (tid < 3) cst[tid] = rp[tid][0] + Wub[tid];
        return;
    }
    const int kk = tid & 63, qm = tid >> 6;
    const int k = blockIdx.x * 64 + kk;
    const float* src; size_t ld;
    if (blockIdx.x < CH0) { src = Wy + k; ld = RR; }
    else { src = Whw + (k - RR); ld = HH; }
    float a0 = 0, a1 = 0, a2 = 0;
    for (int m = qm * 256; m < qm * 256 + 256; ++m) {
        const float val = src[(size_t)m * ld];
        a0 += sWu[m] * val; a1 += sWu[HH + m] * val; a2 += sWu[2 * HH + m] * val;
    }
    part[qm][0][kk] = a0; part[qm][1][kk] = a1; part[qm][2][kk] = a2;
    __syncthreads();
    if (tid < 192) {
        const int j = tid >> 6, k2 = tid & 63;
        const float s = part[0][j][k2] + part[1][j][k2] + part[2][j][k2] + part[3][j][k2];
        Wyu16[(size_t)j * KT + blockIdx.x * 64 + k2] = (_Float16)s;
    }
}

extern "C" void kernel_launch(void* const* d_in, const int* in_sizes, int n_in,
                              void* d_out, int out_size, void* d_ws, size_t ws_size,
                              hipStream_t stream) {
    (void)in_sizes; (void)n_in; (void)out_size;
    const float* feature = (const float*)d_in[0];
    const float* attn_Wx = (const float*)d_in[1];
    const float* attn_Wh = (const float*)d_in[2];
    const float* attn_v  = (const float*)d_in[3];
    const float* W_ih    = (const float*)d_in[4];
    const float* W_hh    = (const float*)d_in[5];
    const float* b_ih    = (const float*)d_in[6];
    const float* b_hh    = (const float*)d_in[7];
    const float* Wh_w    = (const float*)d_in[8];
    const float* Wh_b    = (const float*)d_in[9];
    const float* Wy_w    = (const float*)d_in[10];
    const float* Wu_w    = (const float*)d_in[11];
    const float* Wu_b    = (const float*)d_in[12];
    const float* iWh_w   = (const float*)d_in[13];
    const float* iWh_b   = (const float*)d_in[14];
    const float* iWc_w   = (const float*)d_in[15];
    const float* iWc_b   = (const float*)d_in[16];
    float* out = (float*)d_out;

    char* ws = (char*)d_ws;
    size_t off = 0;
    auto alloc = [&](size_t bytes) { void* p = ws + off; off += (bytes + 255) & ~(size_t)255; return p; };
    _Float16* Wih16 = (_Float16*)alloc((size_t)NG * RR * 2);
    _Float16* Whh16 = (_Float16*)alloc((size_t)NG * HH * 2);
    _Float16* WxT16 = (_Float16*)alloc((size_t)DD * DD * 2);
    _Float16* V16   = (_Float16*)alloc((size_t)TT * NB * RR * 2);
    float*    hbuf  = (float*)alloc((size_t)NB * HH * 4);
    float*    cbuf  = (float*)alloc((size_t)NB * HH * 4);
    _Float16* h16   = (_Float16*)alloc((size_t)NB * HH * 2);
    float*    gpart = (float*)alloc((size_t)4 * NB * NG * 4);
    _Float16* Wyu16 = (_Float16*)alloc((size_t)3 * KT * 2);
    float*    vpart = (float*)alloc((size_t)TT * NB * 3 * 4);
    float*    hpart = (float*)alloc((size_t)TT * NB * 3 * 4);
    float*    cstb  = (float*)alloc(16);
    if (ws_size < off) return;   // refuse to scribble out of bounds

    // one-time: weight conversion + head-weight fusion (+Wx transpose) + init
    const int nconv = NG * RR + NG * HH;
    k_conv2<<<(nconv / 4 + 255) / 256, 256, 0, stream>>>(W_ih, Wih16, NG * RR,
                                                         W_hh, Whh16, NG * HH);
    k_wfuse<<<CHT + 2, 256, 0, stream>>>(Wy_w, Wh_w, Wu_w, Wh_b, Wu_b, Wyu16, cstb,
                                         attn_Wx, WxT16);
    k_init<<<64, 256, 0, stream>>>(feature, iWh_w, iWh_b, iWc_w, iWc_b, hbuf, cbuf, h16);

    // attention for t=0 from h0
    k_step<<<64, 512, 0, stream>>>(0, 0, gpart, b_ih, b_hh, cbuf, h16, hbuf,
                                   feature, WxT16, attn_Wh, attn_v, V16, Wyu16,
                                   vpart, hpart, cstb, out);
    for (int t = 0; t < TT; ++t) {
        const _Float16* Vt = V16 + (size_t)t * NB * RR;
        k_gemm<64, 4><<<256, 128, 0, stream>>>(Vt, h16, Wih16, Whh16,
                                               gpart, NG, (size_t)NB * NG);
        k_step<<<64, 512, 0, stream>>>(t + 1, 1, gpart, b_ih, b_hh, cbuf, h16, hbuf,
                                       feature, WxT16, attn_Wh, attn_v, V16, Wyu16,
                                       vpart, hpart, cstb, out);
    }
}

// Round 13
// 591.186 us; speedup vs baseline: 1.0378x; 1.0378x over previous
//
#include <hip/hip_runtime.h>
#include <math.h>

typedef _Float16 half8 __attribute__((ext_vector_type(8)));
typedef _Float16 half4v __attribute__((ext_vector_type(4)));
typedef _Float16 half2v __attribute__((ext_vector_type(2)));
typedef float floatx16 __attribute__((ext_vector_type(16)));
typedef float floatx4 __attribute__((ext_vector_type(4)));

#define TT 20
#define NB 64      // batch per step
#define LL 90
#define DD 64
#define RR 5760    // L*D
#define HH 1024
#define NG 4096    // 4*H
#define KT 6784    // RR + HH
#define CH0 90     // chunks in K-part0 (5760/64)
#define CHT 106    // total 64-half chunks (6784/64)
#define SPLITK 8

__device__ __forceinline__ float sigm(float x) { return 1.f / (1.f + expf(-x)); }

// ---------------- fp32 -> fp16 convert ----------------
__global__ __launch_bounds__(256) void k_conv(const float* __restrict__ s,
                                              _Float16* __restrict__ d, int n) {
    int i = (blockIdx.x * 256 + threadIdx.x) * 4;
    if (i + 4 <= n) {
        const float4 v = *(const float4*)(s + i);
        half4v o;
        o[0] = (_Float16)v.x; o[1] = (_Float16)v.y;
        o[2] = (_Float16)v.z; o[3] = (_Float16)v.w;
        *(half4v*)(d + i) = o;
    } else {
        for (; i < n; ++i) d[i] = (_Float16)s[i];
    }
}

// ---------------- init h0, c0 ----------------
__global__ __launch_bounds__(256) void k_init(const float* __restrict__ feat,
        const float* __restrict__ iWh_w, const float* __restrict__ iWh_b,
        const float* __restrict__ iWc_w, const float* __restrict__ iWc_b,
        float* __restrict__ h, float* __restrict__ c, _Float16* __restrict__ h16) {
    __shared__ float f0p[4][DD];
    __shared__ float f0[DD];
    const int b = blockIdx.x, tid = threadIdx.x;
    const int dd = tid & 63, lg = tid >> 6;
    const float* frow = feat + (size_t)(b * TT) * RR;   // t = 0
    float p = 0;
    for (int l = lg; l < LL; l += 4) p += frow[l * DD + dd];
    f0p[lg][dd] = p;
    __syncthreads();
    if (tid < DD) f0[tid] = (f0p[0][tid] + f0p[1][tid] + f0p[2][tid] + f0p[3][tid]) * (1.0f / LL);
    __syncthreads();
    for (int o = tid; o < HH; o += 256) {
        float ah = iWh_b[o], ac = iWc_b[o];
        for (int d0 = 0; d0 < DD; d0 += 4) {
            const float4 wh = *(const float4*)(iWh_w + (size_t)o * DD + d0);
            const float4 wc = *(const float4*)(iWc_w + (size_t)o * DD + d0);
            ah += f0[d0] * wh.x + f0[d0 + 1] * wh.y + f0[d0 + 2] * wh.z + f0[d0 + 3] * wh.w;
            ac += f0[d0] * wc.x + f0[d0 + 1] * wc.y + f0[d0 + 2] * wc.z + f0[d0 + 3] * wc.w;
        }
        const float hv = tanhf(ah), cv = tanhf(ac);
        h[b * HH + o] = hv; c[b * HH + o] = cv;
        h16[b * HH + o] = (_Float16)hv;
    }
}

// ===== fused LSTM cell (step tattn-1, if do_cell) + attention for step tattn =====
// 64 blocks (one per batch b) x 512 threads. xproj computed in-block via MFMA.
__global__ __launch_bounds__(512) void k_step(int tattn, int do_cell,
        const float* __restrict__ gpart, const float* __restrict__ b_ih,
        const float* __restrict__ b_hh, float* __restrict__ cbuf,
        _Float16* __restrict__ h16, _Float16* __restrict__ H16,
        const float* __restrict__ h0buf, const float* __restrict__ feat,
        const _Float16* __restrict__ WxTg, const float* __restrict__ Wh,
        const float* __restrict__ v, _Float16* __restrict__ V16) {
    __shared__ float sf[RR];               // feature row fp32 (23 KB)
    __shared__ _Float16 x16[96 * DD];      // feature row fp16, rows 90..95 zero (12 KB)
    __shared__ _Float16 wxT[DD * DD];      // WxT[a][d] fp16 (8 KB)
    __shared__ float sh[HH];
    __shared__ float hWhp[8][DD];
    __shared__ float hWh[DD];
    __shared__ float sv[DD];
    __shared__ float se[128];
    __shared__ float red[128];
    __shared__ float salpha[LL];
    const int b = blockIdx.x, tid = threadIdx.x;
    const int t = tattn;
    if (tid < DD) sv[tid] = v[tid];

    if (t < TT) {   // stage feature row (fp32 + fp16) and WxT
        const float* frow = feat + ((size_t)b * TT + t) * RR;
        for (int e = tid * 4; e < RR; e += 2048) {
            const float4 u = *(const float4*)(frow + e);
            *(float4*)(sf + e) = u;
            half4v o;
            o[0] = (_Float16)u.x; o[1] = (_Float16)u.y;
            o[2] = (_Float16)u.z; o[3] = (_Float16)u.w;
            *(half4v*)(x16 + e) = o;
        }
        if (tid < 48) *(half8*)(x16 + RR + tid * 8) = half8{0,0,0,0,0,0,0,0};
        *(half8*)(wxT + tid * 8) = *(const half8*)(WxTg + tid * 8);
    }

    if (do_cell) {
        // ----- cell for step t-1: 2 hidden units per thread, 8 split-K partials -----
        const int j0 = tid * 2;
        float ag[4][2];
#pragma unroll
        for (int g = 0; g < 4; ++g) { ag[g][0] = 0.f; ag[g][1] = 0.f; }
#pragma unroll
        for (int sp = 0; sp < SPLITK; ++sp) {
            const float* P = gpart + ((size_t)sp * NB + b) * NG;
#pragma unroll
            for (int g = 0; g < 4; ++g) {
                const float2 pv = *(const float2*)(P + g * HH + j0);
                ag[g][0] += pv.x; ag[g][1] += pv.y;
            }
        }
#pragma unroll
        for (int g = 0; g < 4; ++g) {
            const float2 bi = *(const float2*)(b_ih + g * HH + j0);
            const float2 bh = *(const float2*)(b_hh + g * HH + j0);
            ag[g][0] += bi.x + bh.x; ag[g][1] += bi.y + bh.y;
        }
        const float2 cold = *(const float2*)(cbuf + (size_t)b * HH + j0);
        float co[2] = { cold.x, cold.y };
        float2 cnew; half2v hh2;
#pragma unroll
        for (int q = 0; q < 2; ++q) {
            const float cv = sigm(ag[1][q]) * co[q] + sigm(ag[0][q]) * tanhf(ag[2][q]);
            const float hv = sigm(ag[3][q]) * tanhf(cv);
            ((float*)&cnew)[q] = cv;
            hh2[q] = (_Float16)hv;
            sh[j0 + q] = hv;
        }
        *(float2*)(cbuf + (size_t)b * HH + j0) = cnew;
        *(half2v*)(h16 + (size_t)b * HH + j0) = hh2;
        *(half2v*)(H16 + ((size_t)(t - 1) * NB + b) * HH + j0) = hh2;
    } else {
        for (int e = tid; e < HH; e += 512) sh[e] = h0buf[(size_t)b * HH + e];
    }
    __syncthreads();
    if (t >= TT) return;

    // ----- hWh = h @ Wh : 8-way K-split, coalesced 256B wave loads (fp32 Wh) -----
    { const int a = tid & 63, q = tid >> 6;           // q in 0..7
      const float* Wq = Wh + (size_t)(q * 128) * DD + a;
      const float* shq = sh + q * 128;
      float p0 = 0.f, p1 = 0.f;
#pragma unroll 8
      for (int k = 0; k < 128; k += 2) {
          p0 += shq[k] * Wq[(size_t)k * DD];
          p1 += shq[k + 1] * Wq[(size_t)(k + 1) * DD];
      }
      hWhp[q][a] = p0 + p1; }
    __syncthreads();
    if (tid < DD) {
        float s = 0.f;
#pragma unroll
        for (int q = 0; q < 8; ++q) s += hWhp[q][tid];
        hWh[tid] = s;
    }
    if (tid < 128) se[tid] = -1e30f;
    __syncthreads();

    // ----- e via MFMA: waves 0..5, l-tile = w*16; D[l][a] col=ln&15, row=(ln>>4)*4+q -----
    { const int w = tid >> 6, ln = tid & 63;
      if (w < 6) {
          const int l0 = w * 16, c = ln & 15, g = ln >> 4;
          float es[4] = {0.f, 0.f, 0.f, 0.f};
#pragma unroll
          for (int at = 0; at < 4; ++at) {
              floatx4 acc = {0.f, 0.f, 0.f, 0.f};
#pragma unroll
              for (int kk = 0; kk < 2; ++kk) {
                  const half8 af = *(const half8*)(x16 + (l0 + c) * DD + g * 8 + kk * 32);
                  const half8 bf = *(const half8*)(wxT + (at * 16 + c) * DD + g * 8 + kk * 32);
                  acc = __builtin_amdgcn_mfma_f32_16x16x32_f16(af, bf, acc, 0, 0, 0);
              }
#pragma unroll
              for (int q = 0; q < 4; ++q) {
                  const int aa = at * 16 + c;
                  es[q] += tanhf(acc[q] + hWh[aa]) * sv[aa];
              }
          }
#pragma unroll
          for (int q = 0; q < 4; ++q) {
              es[q] += __shfl_xor(es[q], 1, 64);
              es[q] += __shfl_xor(es[q], 2, 64);
              es[q] += __shfl_xor(es[q], 4, 64);
              es[q] += __shfl_xor(es[q], 8, 64);
          }
          if (c == 0) {
#pragma unroll
              for (int q = 0; q < 4; ++q) {
                  const int l = l0 + g * 4 + q;
                  if (l < LL) se[l] = es[q];
              }
          }
      } }
    __syncthreads();

    // ----- softmax over se[0..89] -----
    if (tid < 128) red[tid] = se[tid];
    __syncthreads();
    for (int s = 64; s; s >>= 1) { if (tid < s) red[tid] = fmaxf(red[tid], red[tid + s]); __syncthreads(); }
    const float mx = red[0];
    __syncthreads();
    float ex = 0.f;
    if (tid < LL) { ex = expf(se[tid] - mx); salpha[tid] = ex; }
    if (tid < 128) red[tid] = ex;
    __syncthreads();
    for (int s = 64; s; s >>= 1) { if (tid < s) red[tid] += red[tid + s]; __syncthreads(); }
    const float inv = 1.f / red[0];
    __syncthreads();
    if (tid < LL) salpha[tid] *= inv;
    __syncthreads();

    // ----- visual write from the LDS fp32 feature row -----
    _Float16* vout = V16 + ((size_t)t * NB + b) * RR;
    for (int e = tid * 4; e < RR; e += 2048) {
        const float4 u4 = *(const float4*)(sf + e);
        const float al = salpha[e >> 6];
        half4v o;
        o[0] = (_Float16)(u4.x * al); o[1] = (_Float16)(u4.y * al);
        o[2] = (_Float16)(u4.z * al); o[3] = (_Float16)(u4.w * al);
        *(half4v*)(vout + e) = o;
    }
}

// ================= tiled GEMM machinery (gates) =================
__device__ __forceinline__ void stage_tile(const char* src, size_t stride, char* lds, int ln) {
    const char* g = src + (size_t)(ln >> 3) * stride + (((ln & 7) ^ (ln >> 3)) << 4);
#pragma unroll
    for (int i = 0; i < 8; ++i)
        __builtin_amdgcn_global_load_lds(
            (const __attribute__((address_space(1))) void*)(g + (size_t)(i * 8) * stride),
            (__attribute__((address_space(3))) void*)(lds + i * 1024), 16, 0, 0);
}

struct Src2 { const char* p0; size_t s0; const char* p1; size_t s1; };

__device__ __forceinline__ const char* chunk_ptr(const Src2& s, int c, size_t& stride) {
    if (c < CH0) { stride = s.s0; return s.p0 + (size_t)c * 128; }
    stride = s.s1; return s.p1 + (size_t)(c - CH0) * 128;
}

template<int NT, int SB>
__global__ __launch_bounds__(128) void k_gemm(
        const _Float16* __restrict__ A0, const _Float16* __restrict__ A1,
        const _Float16* __restrict__ B0, const _Float16* __restrict__ B1,
        float* __restrict__ C, int ldc, size_t part_elems) {
    __shared__ char smem[65536];
    const int bid = blockIdx.x;
    const int kb = bid % SB;
    const int nt = (bid / SB) % NT;
    const int mt = bid / (SB * NT);
    const int tid = threadIdx.x, w = tid >> 6, ln = tid & 63;
    char* wlds = smem + w * 32768;

    const int arow = mt * 64, brow = nt * 64;
    Src2 As = { (const char*)(A0 + (size_t)arow * RR), (size_t)RR * 2,
                (const char*)(A1 + (size_t)arow * HH), (size_t)HH * 2 };
    Src2 Bs = { (const char*)(B0 + (size_t)brow * RR), (size_t)RR * 2,
                (const char*)(B1 + (size_t)brow * HH), (size_t)HH * 2 };

    floatx16 acc00, acc01, acc10, acc11;
#pragma unroll
    for (int i = 0; i < 16; ++i) { acc00[i] = 0.f; acc01[i] = 0.f; acc10[i] = 0.f; acc11[i] = 0.f; }

    const int start = kb * 2 + w;
    const int STRIDE = SB * 2;
    const int r = ln & 31;
    const int xsw = (r & 7) << 4;
    const int fo = (ln >> 5) * 16;
    const int rbyte = r * 128;

    int c = start, bsel = 0;
    { size_t st; const char* p = chunk_ptr(As, c, st); stage_tile(p, st, wlds, ln);
      p = chunk_ptr(Bs, c, st); stage_tile(p, st, wlds + 8192, ln); }
    while (true) {
        const int cn = c + STRIDE;
        if (cn < CHT) {
            char* nl = wlds + ((bsel ^ 1) << 14);
            size_t st; const char* p = chunk_ptr(As, cn, st); stage_tile(p, st, nl, ln);
            p = chunk_ptr(Bs, cn, st); stage_tile(p, st, nl + 8192, ln);
            asm volatile("s_waitcnt vmcnt(16)" ::: "memory");
        } else {
            asm volatile("s_waitcnt vmcnt(0)" ::: "memory");
        }
        __builtin_amdgcn_sched_barrier(0);
        const char* LA = wlds + (bsel << 14);
        const char* LB = LA + 8192;
#pragma unroll
        for (int kk = 0; kk < 4; ++kk) {
            const int o = ((kk * 32 + fo) ^ xsw);
            const half8 a0 = *(const half8*)(LA + rbyte + o);
            const half8 a1 = *(const half8*)(LA + 4096 + rbyte + o);
            const half8 b0 = *(const half8*)(LB + rbyte + o);
            const half8 b1 = *(const half8*)(LB + 4096 + rbyte + o);
            acc00 = __builtin_amdgcn_mfma_f32_32x32x16_f16(a0, b0, acc00, 0, 0, 0);
            acc01 = __builtin_amdgcn_mfma_f32_32x32x16_f16(a0, b1, acc01, 0, 0, 0);
            acc10 = __builtin_amdgcn_mfma_f32_32x32x16_f16(a1, b0, acc10, 0, 0, 0);
            acc11 = __builtin_amdgcn_mfma_f32_32x32x16_f16(a1, b1, acc11, 0, 0, 0);
        }
        if (cn >= CHT) break;
        c = cn; bsel ^= 1;
    }
    __syncthreads();
    float* Rg = (float*)(smem + w * 16384);
    const int rbase = 4 * (ln >> 5), lr = ln & 31;
#pragma unroll
    for (int q = 0; q < 16; ++q) {
        const int row = rbase + (q & 3) + 8 * (q >> 2);
        Rg[row * 64 + lr]             = acc00[q];
        Rg[row * 64 + 32 + lr]        = acc01[q];
        Rg[(row + 32) * 64 + lr]      = acc10[q];
        Rg[(row + 32) * 64 + 32 + lr] = acc11[q];
    }
    __syncthreads();
    const float* R0 = (const float*)smem;
    const float* R1 = (const float*)(smem + 16384);
    float* Cout = C + (size_t)kb * part_elems;
    for (int e = tid * 4; e < 4096; e += 512) {
        const float4 u = *(const float4*)(R0 + e);
        const float4 v2 = *(const float4*)(R1 + e);
        float4 s2; s2.x = u.x + v2.x; s2.y = u.y + v2.y; s2.z = u.z + v2.z; s2.w = u.w + v2.w;
        const int row = e >> 6, col = e & 63;
        *(float4*)(Cout + (size_t)(arow + row) * ldc + brow + col) = s2;
    }
}

// ===== Wu-fused head weights: Wyu16[j] = Wu @ [Wy | Whw], cst[j]; + Wx transpose =====
__global__ __launch_bounds__(256) void k_wfuse(const float* __restrict__ Wy,
        const float* __restrict__ Whw, const float* __restrict__ Wu,
        const float* __restrict__ Whb, const float* __restrict__ Wub,
        _Float16* __restrict__ Wyu16, float* __restrict__ cst,
        const float* __restrict__ Wx, _Float16* __restrict__ WxT) {
    const int tid = threadIdx.x;
    if (blockIdx.x == CHT + 1) {   // WxT[a][d] = Wx[d][a] fp16
        const int a = tid >> 2, k0 = (tid & 3) * 16;
#pragma unroll
        for (int j = 0; j < 16; ++j)
            WxT[(size_t)a * DD + k0 + j] = (_Float16)Wx[(size_t)(k0 + j) * DD + a];
        return;
    }
    __shared__ float sWu[3 * HH];
    __shared__ float part[4][3][64];
    for (int e = tid * 4; e < 3 * HH; e += 1024)
        *(float4*)(sWu + e) = *(const float4*)(Wu + e);
    __syncthreads();
    if (blockIdx.x == CHT) {   // cst block
        float a0 = 0, a1 = 0, a2 = 0;
        for (int m = tid; m < HH; m += 256) {
            const float wb = Whb[m];
            a0 += sWu[m] * wb; a1 += sWu[HH + m] * wb; a2 += sWu[2 * HH + m] * wb;
        }
        __shared__ float rp[3][256];
        rp[0][tid] = a0; rp[1][tid] = a1; rp[2][tid] = a2;
        __syncthreads();
        for (int s = 128; s; s >>= 1) {
            if (tid < s) { rp[0][tid] += rp[0][tid + s]; rp[1][tid] += rp[1][tid + s]; rp[2][tid] += rp[2][tid + s]; }
            __syncthreads();
        }
        if (tid < 3) cst[tid] = rp[tid][0] + Wub[tid];
        return;
    }
    const int kk = tid & 63, qm = tid >> 6;
    const int k = blockIdx.x * 64 + kk;
    const float* src; size_t ld;
    if (blockIdx.x < CH0) { src = Wy + k; ld = RR; }
    else { src = Whw + (k - RR); ld = HH; }
    float a0 = 0, a1 = 0, a2 = 0;
    for (int m = qm * 256; m < qm * 256 + 256; ++m) {
        const float val = src[(size_t)m * ld];
        a0 += sWu[m] * val; a1 += sWu[HH + m] * val; a2 += sWu[2 * HH + m] * val;
    }
    part[qm][0][kk] = a0; part[qm][1][kk] = a1; part[qm][2][kk] = a2;
    __syncthreads();
    if (tid < 192) {
        const int j = tid >> 6, k2 = tid & 63;
        const float s = part[0][j][k2] + part[1][j][k2] + part[2][j][k2] + part[3][j][k2];
        Wyu16[(size_t)j * KT + blockIdx.x * 64 + k2] = (_Float16)s;
    }
}

// ===== final: out[r][j] = V16[r].Wyu[j][:5760] + H16[r].Wyu[j][5760:] + cst[j] =====
__global__ __launch_bounds__(256) void k_final2(const _Float16* __restrict__ V16,
        const _Float16* __restrict__ H16, const _Float16* __restrict__ Wyu,
        const float* __restrict__ cst, float* __restrict__ out) {
    __shared__ float rp[4][3];
    const int r = blockIdx.x, tid = threadIdx.x;   // r = t*64 + b
    const _Float16* vrow = V16 + (size_t)r * RR;
    const _Float16* hrow = H16 + (size_t)r * HH;
    float a0 = 0, a1 = 0, a2 = 0;
    for (int e = tid * 8; e < KT; e += 2048) {
        half8 x;
        if (e < RR) x = *(const half8*)(vrow + e);
        else        x = *(const half8*)(hrow + (e - RR));
        const half8 w0 = *(const half8*)(Wyu + e);
        const half8 w1 = *(const half8*)(Wyu + KT + e);
        const half8 w2 = *(const half8*)(Wyu + 2 * KT + e);
#pragma unroll
        for (int i = 0; i < 8; ++i) {
            const float xv = (float)x[i];
            a0 += xv * (float)w0[i]; a1 += xv * (float)w1[i]; a2 += xv * (float)w2[i];
        }
    }
    for (int o = 32; o > 0; o >>= 1) {
        a0 += __shfl_down(a0, o, 64); a1 += __shfl_down(a1, o, 64); a2 += __shfl_down(a2, o, 64);
    }
    const int wv = tid >> 6;
    if ((tid & 63) == 0) { rp[wv][0] = a0; rp[wv][1] = a1; rp[wv][2] = a2; }
    __syncthreads();
    if (tid < 3) {
        const float x = rp[0][tid] + rp[1][tid] + rp[2][tid] + rp[3][tid] + cst[tid];
        const int b = r & 63, ts = r >> 6;
        out[((size_t)b * TT + ts) * 3 + tid] = x;
    }
}

extern "C" void kernel_launch(void* const* d_in, const int* in_sizes, int n_in,
                              void* d_out, int out_size, void* d_ws, size_t ws_size,
                              hipStream_t stream) {
    (void)in_sizes; (void)n_in; (void)out_size;
    const float* feature = (const float*)d_in[0];
    const float* attn_Wx = (const float*)d_in[1];
    const float* attn_Wh = (const float*)d_in[2];
    const float* attn_v  = (const float*)d_in[3];
    const float* W_ih    = (const float*)d_in[4];
    const float* W_hh    = (const float*)d_in[5];
    const float* b_ih    = (const float*)d_in[6];
    const float* b_hh    = (const float*)d_in[7];
    const float* Wh_w    = (const float*)d_in[8];
    const float* Wh_b    = (const float*)d_in[9];
    const float* Wy_w    = (const float*)d_in[10];
    const float* Wu_w    = (const float*)d_in[11];
    const float* Wu_b    = (const float*)d_in[12];
    const float* iWh_w   = (const float*)d_in[13];
    const float* iWh_b   = (const float*)d_in[14];
    const float* iWc_w   = (const float*)d_in[15];
    const float* iWc_b   = (const float*)d_in[16];
    float* out = (float*)d_out;

    char* ws = (char*)d_ws;
    size_t off = 0;
    auto alloc = [&](size_t bytes) { void* p = ws + off; off += (bytes + 255) & ~(size_t)255; return p; };
    _Float16* Wih16 = (_Float16*)alloc((size_t)NG * RR * 2);
    _Float16* Whh16 = (_Float16*)alloc((size_t)NG * HH * 2);
    _Float16* WxT16 = (_Float16*)alloc((size_t)DD * DD * 2);
    _Float16* V16   = (_Float16*)alloc((size_t)TT * NB * RR * 2);
    _Float16* H16   = (_Float16*)alloc((size_t)TT * NB * HH * 2);
    float*    hbuf  = (float*)alloc((size_t)NB * HH * 4);
    float*    cbuf  = (float*)alloc((size_t)NB * HH * 4);
    _Float16* h16   = (_Float16*)alloc((size_t)NB * HH * 2);
    float*    gpart = (float*)alloc((size_t)SPLITK * NB * NG * 4);
    _Float16* Wyu16 = (_Float16*)alloc((size_t)3 * KT * 2);
    float*    cstb  = (float*)alloc(16);
    if (ws_size < off) return;   // refuse to scribble out of bounds

    // one-time: weight conversions + head-weight fusion (+Wx transpose) + init
    k_conv<<<(NG * RR / 4 + 255) / 256, 256, 0, stream>>>(W_ih, Wih16, NG * RR);
    k_conv<<<(NG * HH / 4 + 255) / 256, 256, 0, stream>>>(W_hh, Whh16, NG * HH);
    k_wfuse<<<CHT + 2, 256, 0, stream>>>(Wy_w, Wh_w, Wu_w, Wh_b, Wu_b, Wyu16, cstb,
                                         attn_Wx, WxT16);
    k_init<<<64, 256, 0, stream>>>(feature, iWh_w, iWh_b, iWc_w, iWc_b, hbuf, cbuf, h16);

    // attention for t=0 from h0
    k_step<<<64, 512, 0, stream>>>(0, 0, gpart, b_ih, b_hh, cbuf, h16, H16, hbuf,
                                   feature, WxT16, attn_Wh, attn_v, V16);
    for (int t = 0; t < TT; ++t) {
        const _Float16* Vt = V16 + (size_t)t * NB * RR;
        k_gemm<64, SPLITK><<<64 * SPLITK, 128, 0, stream>>>(Vt, h16, Wih16, Whh16,
                                                            gpart, NG, (size_t)NB * NG);
        k_step<<<64, 512, 0, stream>>>(t + 1, 1, gpart, b_ih, b_hh, cbuf, h16, H16, hbuf,
                                       feature, WxT16, attn_Wh, attn_v, V16);
    }

    k_final2<<<1280, 256, 0, stream>>>(V16, H16, Wyu16, cstb, out);
}

// Round 14
// 571.598 us; speedup vs baseline: 1.0734x; 1.0343x over previous
//
#include <hip/hip_runtime.h>
#include <math.h>

typedef _Float16 half8 __attribute__((ext_vector_type(8)));
typedef _Float16 half4v __attribute__((ext_vector_type(4)));
typedef _Float16 half2v __attribute__((ext_vector_type(2)));
typedef float floatx16 __attribute__((ext_vector_type(16)));
typedef float floatx4 __attribute__((ext_vector_type(4)));

#define TT 20
#define NB 64      // batch per step
#define LL 90
#define DD 64
#define RR 5760    // L*D
#define HH 1024
#define NG 4096    // 4*H
#define KT 6784    // RR + HH
#define CH0 90     // chunks in K-part0 (5760/64)
#define CHT 106    // total 64-half chunks (6784/64)

__device__ __forceinline__ float sigm(float x) { return 1.f / (1.f + expf(-x)); }

// ---------------- fp32 -> fp16 convert ----------------
__global__ __launch_bounds__(256) void k_conv(const float* __restrict__ s,
                                              _Float16* __restrict__ d, int n) {
    int i = (blockIdx.x * 256 + threadIdx.x) * 4;
    if (i + 4 <= n) {
        const float4 v = *(const float4*)(s + i);
        half4v o;
        o[0] = (_Float16)v.x; o[1] = (_Float16)v.y;
        o[2] = (_Float16)v.z; o[3] = (_Float16)v.w;
        *(half4v*)(d + i) = o;
    } else {
        for (; i < n; ++i) d[i] = (_Float16)s[i];
    }
}

// ---------------- init h0, c0 ----------------
__global__ __launch_bounds__(256) void k_init(const float* __restrict__ feat,
        const float* __restrict__ iWh_w, const float* __restrict__ iWh_b,
        const float* __restrict__ iWc_w, const float* __restrict__ iWc_b,
        float* __restrict__ h, float* __restrict__ c, _Float16* __restrict__ h16) {
    __shared__ float f0p[4][DD];
    __shared__ float f0[DD];
    const int b = blockIdx.x, tid = threadIdx.x;
    const int dd = tid & 63, lg = tid >> 6;
    const float* frow = feat + (size_t)(b * TT) * RR;   // t = 0
    float p = 0;
    for (int l = lg; l < LL; l += 4) p += frow[l * DD + dd];
    f0p[lg][dd] = p;
    __syncthreads();
    if (tid < DD) f0[tid] = (f0p[0][tid] + f0p[1][tid] + f0p[2][tid] + f0p[3][tid]) * (1.0f / LL);
    __syncthreads();
    for (int o = tid; o < HH; o += 256) {
        float ah = iWh_b[o], ac = iWc_b[o];
        for (int d0 = 0; d0 < DD; d0 += 4) {
            const float4 wh = *(const float4*)(iWh_w + (size_t)o * DD + d0);
            const float4 wc = *(const float4*)(iWc_w + (size_t)o * DD + d0);
            ah += f0[d0] * wh.x + f0[d0 + 1] * wh.y + f0[d0 + 2] * wh.z + f0[d0 + 3] * wh.w;
            ac += f0[d0] * wc.x + f0[d0 + 1] * wc.y + f0[d0 + 2] * wc.z + f0[d0 + 3] * wc.w;
        }
        const float hv = tanhf(ah), cv = tanhf(ac);
        h[b * HH + o] = hv; c[b * HH + o] = cv;
        h16[b * HH + o] = (_Float16)hv;
    }
}

// ===== fused LSTM cell (step tattn-1, if do_cell) + attention for step tattn =====
// 64 blocks (one per batch b) x 512 threads. xproj computed in-block via MFMA.
__global__ __launch_bounds__(512) void k_step(int tattn, int do_cell,
        const float* __restrict__ gpart, const float* __restrict__ b_ih,
        const float* __restrict__ b_hh, float* __restrict__ cbuf,
        _Float16* __restrict__ h16, _Float16* __restrict__ H16,
        const float* __restrict__ h0buf, const float* __restrict__ feat,
        const _Float16* __restrict__ WxTg, const float* __restrict__ Wh,
        const float* __restrict__ v, _Float16* __restrict__ V16) {
    __shared__ float sf[RR];               // feature row fp32 (23 KB)
    __shared__ _Float16 x16[96 * DD];      // feature row fp16, rows 90..95 zero (12 KB)
    __shared__ _Float16 wxT[DD * DD];      // WxT[a][d] fp16 (8 KB)
    __shared__ float sh[HH];
    __shared__ float hWhp[8][DD];
    __shared__ float hWh[DD];
    __shared__ float sv[DD];
    __shared__ float se[128];
    __shared__ float red[128];
    __shared__ float salpha[LL];
    const int b = blockIdx.x, tid = threadIdx.x;
    const int t = tattn;
    if (tid < DD) sv[tid] = v[tid];

    if (t < TT) {   // stage feature row (fp32 + fp16) and WxT
        const float* frow = feat + ((size_t)b * TT + t) * RR;
        for (int e = tid * 4; e < RR; e += 2048) {
            const float4 u = *(const float4*)(frow + e);
            *(float4*)(sf + e) = u;
            half4v o;
            o[0] = (_Float16)u.x; o[1] = (_Float16)u.y;
            o[2] = (_Float16)u.z; o[3] = (_Float16)u.w;
            *(half4v*)(x16 + e) = o;
        }
        if (tid < 48) *(half8*)(x16 + RR + tid * 8) = half8{0,0,0,0,0,0,0,0};
        *(half8*)(wxT + tid * 8) = *(const half8*)(WxTg + tid * 8);
    }

    if (do_cell) {
        // ----- cell for step t-1: 2 hidden units per thread, 4 split-K partials -----
        const int j0 = tid * 2;
        float ag[4][2];
#pragma unroll
        for (int g = 0; g < 4; ++g) { ag[g][0] = 0.f; ag[g][1] = 0.f; }
#pragma unroll
        for (int sp = 0; sp < 4; ++sp) {
            const float* P = gpart + ((size_t)sp * NB + b) * NG;
#pragma unroll
            for (int g = 0; g < 4; ++g) {
                const float2 pv = *(const float2*)(P + g * HH + j0);
                ag[g][0] += pv.x; ag[g][1] += pv.y;
            }
        }
#pragma unroll
        for (int g = 0; g < 4; ++g) {
            const float2 bi = *(const float2*)(b_ih + g * HH + j0);
            const float2 bh = *(const float2*)(b_hh + g * HH + j0);
            ag[g][0] += bi.x + bh.x; ag[g][1] += bi.y + bh.y;
        }
        const float2 cold = *(const float2*)(cbuf + (size_t)b * HH + j0);
        float co[2] = { cold.x, cold.y };
        float2 cnew; half2v hh2;
#pragma unroll
        for (int q = 0; q < 2; ++q) {
            const float cv = sigm(ag[1][q]) * co[q] + sigm(ag[0][q]) * tanhf(ag[2][q]);
            const float hv = sigm(ag[3][q]) * tanhf(cv);
            ((float*)&cnew)[q] = cv;
            hh2[q] = (_Float16)hv;
            sh[j0 + q] = hv;
        }
        *(float2*)(cbuf + (size_t)b * HH + j0) = cnew;
        *(half2v*)(h16 + (size_t)b * HH + j0) = hh2;
        *(half2v*)(H16 + ((size_t)(t - 1) * NB + b) * HH + j0) = hh2;
    } else {
        for (int e = tid; e < HH; e += 512) sh[e] = h0buf[(size_t)b * HH + e];
    }
    __syncthreads();
    if (t >= TT) return;

    // ----- hWh = h @ Wh : 8-way K-split, coalesced 256B wave loads (fp32 Wh) -----
    { const int a = tid & 63, q = tid >> 6;           // q in 0..7
      const float* Wq = Wh + (size_t)(q * 128) * DD + a;
      const float* shq = sh + q * 128;
      float p0 = 0.f, p1 = 0.f;
#pragma unroll 8
      for (int k = 0; k < 128; k += 2) {
          p0 += shq[k] * Wq[(size_t)k * DD];
          p1 += shq[k + 1] * Wq[(size_t)(k + 1) * DD];
      }
      hWhp[q][a] = p0 + p1; }
    __syncthreads();
    if (tid < DD) {
        float s = 0.f;
#pragma unroll
        for (int q = 0; q < 8; ++q) s += hWhp[q][tid];
        hWh[tid] = s;
    }
    if (tid < 128) se[tid] = -1e30f;
    __syncthreads();

    // ----- e via MFMA: waves 0..5, l-tile = w*16; D[l][a] col=ln&15, row=(ln>>4)*4+q -----
    { const int w = tid >> 6, ln = tid & 63;
      if (w < 6) {
          const int l0 = w * 16, c = ln & 15, g = ln >> 4;
          float es[4] = {0.f, 0.f, 0.f, 0.f};
#pragma unroll
          for (int at = 0; at < 4; ++at) {
              floatx4 acc = {0.f, 0.f, 0.f, 0.f};
#pragma unroll
              for (int kk = 0; kk < 2; ++kk) {
                  const half8 af = *(const half8*)(x16 + (l0 + c) * DD + g * 8 + kk * 32);
                  const half8 bf = *(const half8*)(wxT + (at * 16 + c) * DD + g * 8 + kk * 32);
                  acc = __builtin_amdgcn_mfma_f32_16x16x32_f16(af, bf, acc, 0, 0, 0);
              }
#pragma unroll
              for (int q = 0; q < 4; ++q) {
                  const int aa = at * 16 + c;
                  es[q] += tanhf(acc[q] + hWh[aa]) * sv[aa];
              }
          }
#pragma unroll
          for (int q = 0; q < 4; ++q) {
              es[q] += __shfl_xor(es[q], 1, 64);
              es[q] += __shfl_xor(es[q], 2, 64);
              es[q] += __shfl_xor(es[q], 4, 64);
              es[q] += __shfl_xor(es[q], 8, 64);
          }
          if (c == 0) {
#pragma unroll
              for (int q = 0; q < 4; ++q) {
                  const int l = l0 + g * 4 + q;
                  if (l < LL) se[l] = es[q];
              }
          }
      } }
    __syncthreads();

    // ----- softmax over se[0..89] -----
    if (tid < 128) red[tid] = se[tid];
    __syncthreads();
    for (int s = 64; s; s >>= 1) { if (tid < s) red[tid] = fmaxf(red[tid], red[tid + s]); __syncthreads(); }
    const float mx = red[0];
    __syncthreads();
    float ex = 0.f;
    if (tid < LL) { ex = expf(se[tid] - mx); salpha[tid] = ex; }
    if (tid < 128) red[tid] = ex;
    __syncthreads();
    for (int s = 64; s; s >>= 1) { if (tid < s) red[tid] += red[tid + s]; __syncthreads(); }
    const float inv = 1.f / red[0];
    __syncthreads();
    if (tid < LL) salpha[tid] *= inv;
    __syncthreads();

    // ----- visual write from the LDS fp32 feature row -----
    _Float16* vout = V16 + ((size_t)t * NB + b) * RR;
    for (int e = tid * 4; e < RR; e += 2048) {
        const float4 u4 = *(const float4*)(sf + e);
        const float al = salpha[e >> 6];
        half4v o;
        o[0] = (_Float16)(u4.x * al); o[1] = (_Float16)(u4.y * al);
        o[2] = (_Float16)(u4.z * al); o[3] = (_Float16)(u4.w * al);
        *(half4v*)(vout + e) = o;
    }
}

// ================= tiled GEMM machinery (gates) =================
__device__ __forceinline__ void stage_tile(const char* src, size_t stride, char* lds, int ln) {
    const char* g = src + (size_t)(ln >> 3) * stride + (((ln & 7) ^ (ln >> 3)) << 4);
#pragma unroll
    for (int i = 0; i < 8; ++i)
        __builtin_amdgcn_global_load_lds(
            (const __attribute__((address_space(1))) void*)(g + (size_t)(i * 8) * stride),
            (__attribute__((address_space(3))) void*)(lds + i * 1024), 16, 0, 0);
}

struct Src2 { const char* p0; size_t s0; const char* p1; size_t s1; };

__device__ __forceinline__ const char* chunk_ptr(const Src2& s, int c, size_t& stride) {
    if (c < CH0) { stride = s.s0; return s.p0 + (size_t)c * 128; }
    stride = s.s1; return s.p1 + (size_t)(c - CH0) * 128;
}

template<int NT, int SB>
__global__ __launch_bounds__(128) void k_gemm(
        const _Float16* __restrict__ A0, const _Float16* __restrict__ A1,
        const _Float16* __restrict__ B0, const _Float16* __restrict__ B1,
        float* __restrict__ C, int ldc, size_t part_elems) {
    __shared__ char smem[65536];
    const int bid = blockIdx.x;
    const int kb = bid % SB;
    const int nt = (bid / SB) % NT;
    const int mt = bid / (SB * NT);
    const int tid = threadIdx.x, w = tid >> 6, ln = tid & 63;
    char* wlds = smem + w * 32768;

    const int arow = mt * 64, brow = nt * 64;
    Src2 As = { (const char*)(A0 + (size_t)arow * RR), (size_t)RR * 2,
                (const char*)(A1 + (size_t)arow * HH), (size_t)HH * 2 };
    Src2 Bs = { (const char*)(B0 + (size_t)brow * RR), (size_t)RR * 2,
                (const char*)(B1 + (size_t)brow * HH), (size_t)HH * 2 };

    floatx16 acc00, acc01, acc10, acc11;
#pragma unroll
    for (int i = 0; i < 16; ++i) { acc00[i] = 0.f; acc01[i] = 0.f; acc10[i] = 0.f; acc11[i] = 0.f; }

    const int start = kb * 2 + w;
    const int STRIDE = SB * 2;
    const int r = ln & 31;
    const int xsw = (r & 7) << 4;
    const int fo = (ln >> 5) * 16;
    const int rbyte = r * 128;

    int c = start, bsel = 0;
    { size_t st; const char* p = chunk_ptr(As, c, st); stage_tile(p, st, wlds, ln);
      p = chunk_ptr(Bs, c, st); stage_tile(p, st, wlds + 8192, ln); }
    while (true) {
        const int cn = c + STRIDE;
        if (cn < CHT) {
            char* nl = wlds + ((bsel ^ 1) << 14);
            size_t st; const char* p = chunk_ptr(As, cn, st); stage_tile(p, st, nl, ln);
            p = chunk_ptr(Bs, cn, st); stage_tile(p, st, nl + 8192, ln);
            asm volatile("s_waitcnt vmcnt(16)" ::: "memory");
        } else {
            asm volatile("s_waitcnt vmcnt(0)" ::: "memory");
        }
        __builtin_amdgcn_sched_barrier(0);
        const char* LA = wlds + (bsel << 14);
        const char* LB = LA + 8192;
#pragma unroll
        for (int kk = 0; kk < 4; ++kk) {
            const int o = ((kk * 32 + fo) ^ xsw);
            const half8 a0 = *(const half8*)(LA + rbyte + o);
            const half8 a1 = *(const half8*)(LA + 4096 + rbyte + o);
            const half8 b0 = *(const half8*)(LB + rbyte + o);
            const half8 b1 = *(const half8*)(LB + 4096 + rbyte + o);
            acc00 = __builtin_amdgcn_mfma_f32_32x32x16_f16(a0, b0, acc00, 0, 0, 0);
            acc01 = __builtin_amdgcn_mfma_f32_32x32x16_f16(a0, b1, acc01, 0, 0, 0);
            acc10 = __builtin_amdgcn_mfma_f32_32x32x16_f16(a1, b0, acc10, 0, 0, 0);
            acc11 = __builtin_amdgcn_mfma_f32_32x32x16_f16(a1, b1, acc11, 0, 0, 0);
        }
        if (cn >= CHT) break;
        c = cn; bsel ^= 1;
    }
    __syncthreads();
    float* Rg = (float*)(smem + w * 16384);
    const int rbase = 4 * (ln >> 5), lr = ln & 31;
#pragma unroll
    for (int q = 0; q < 16; ++q) {
        const int row = rbase + (q & 3) + 8 * (q >> 2);
        Rg[row * 64 + lr]             = acc00[q];
        Rg[row * 64 + 32 + lr]        = acc01[q];
        Rg[(row + 32) * 64 + lr]      = acc10[q];
        Rg[(row + 32) * 64 + 32 + lr] = acc11[q];
    }
    __syncthreads();
    const float* R0 = (const float*)smem;
    const float* R1 = (const float*)(smem + 16384);
    float* Cout = C + (size_t)kb * part_elems;
    for (int e = tid * 4; e < 4096; e += 512) {
        const float4 u = *(const float4*)(R0 + e);
        const float4 v2 = *(const float4*)(R1 + e);
        float4 s2; s2.x = u.x + v2.x; s2.y = u.y + v2.y; s2.z = u.z + v2.z; s2.w = u.w + v2.w;
        const int row = e >> 6, col = e & 63;
        *(float4*)(Cout + (size_t)(arow + row) * ldc + brow + col) = s2;
    }
}

// ===== Wu-fused head weights: Wyu16[j] = Wu @ [Wy | Whw], cst[j]; + Wx transpose =====
__global__ __launch_bounds__(256) void k_wfuse(const float* __restrict__ Wy,
        const float* __restrict__ Whw, const float* __restrict__ Wu,
        const float* __restrict__ Whb, const float* __restrict__ Wub,
        _Float16* __restrict__ Wyu16, float* __restrict__ cst,
        const float* __restrict__ Wx, _Float16* __restrict__ WxT) {
    const int tid = threadIdx.x;
    if (blockIdx.x == CHT + 1) {   // WxT[a][d] = Wx[d][a] fp16
        const int a = tid >> 2, k0 = (tid & 3) * 16;
#pragma unroll
        for (int j = 0; j < 16; ++j)
            WxT[(size_t)a * DD + k0 + j] = (_Float16)Wx[(size_t)(k0 + j) * DD + a];
        return;
    }
    __shared__ float sWu[3 * HH];
    __shared__ float part[4][3][64];
    for (int e = tid * 4; e < 3 * HH; e += 1024)
        *(float4*)(sWu + e) = *(const float4*)(Wu + e);
    __syncthreads();
    if (blockIdx.x == CHT) {   // cst block
        float a0 = 0, a1 = 0, a2 = 0;
        for (int m = tid; m < HH; m += 256) {
            const float wb = Whb[m];
            a0 += sWu[m] * wb; a1 += sWu[HH + m] * wb; a2 += sWu[2 * HH + m] * wb;
        }
        __shared__ float rp[3][256];
        rp[0][tid] = a0; rp[1][tid] = a1; rp[2][tid] = a2;
        __syncthreads();
        for (int s = 128; s; s >>= 1) {
            if (tid < s) { rp[0][tid] += rp[0][tid + s]; rp[1][tid] += rp[1][tid + s]; rp[2][tid] += rp[2][tid + s]; }
            __syncthreads();
        }
        if (tid < 3) cst[tid] = rp[tid][0] + Wub[tid];
        return;
    }
    const int kk = tid & 63, qm = tid >> 6;
    const int k = blockIdx.x * 64 + kk;
    const float* src; size_t ld;
    if (blockIdx.x < CH0) { src = Wy + k; ld = RR; }
    else { src = Whw + (k - RR); ld = HH; }
    float a0 = 0, a1 = 0, a2 = 0;
    for (int m = qm * 256; m < qm * 256 + 256; ++m) {
        const float val = src[(size_t)m * ld];
        a0 += sWu[m] * val; a1 += sWu[HH + m] * val; a2 += sWu[2 * HH + m] * val;
    }
    part[qm][0][kk] = a0; part[qm][1][kk] = a1; part[qm][2][kk] = a2;
    __syncthreads();
    if (tid < 192) {
        const int j = tid >> 6, k2 = tid & 63;
        const float s = part[0][j][k2] + part[1][j][k2] + part[2][j][k2] + part[3][j][k2];
        Wyu16[(size_t)j * KT + blockIdx.x * 64 + k2] = (_Float16)s;
    }
}

// ===== final: out[r][j] = V16[r].Wyu[j][:5760] + H16[r].Wyu[j][5760:] + cst[j] =====
__global__ __launch_bounds__(256) void k_final2(const _Float16* __restrict__ V16,
        const _Float16* __restrict__ H16, const _Float16* __restrict__ Wyu,
        const float* __restrict__ cst, float* __restrict__ out) {
    __shared__ float rp[4][3];
    const int r = blockIdx.x, tid = threadIdx.x;   // r = t*64 + b
    const _Float16* vrow = V16 + (size_t)r * RR;
    const _Float16* hrow = H16 + (size_t)r * HH;
    float a0 = 0, a1 = 0, a2 = 0;
    for (int e = tid * 8; e < KT; e += 2048) {
        half8 x;
        if (e < RR) x = *(const half8*)(vrow + e);
        else        x = *(const half8*)(hrow + (e - RR));
        const half8 w0 = *(const half8*)(Wyu + e);
        const half8 w1 = *(const half8*)(Wyu + KT + e);
        const half8 w2 = *(const half8*)(Wyu + 2 * KT + e);
#pragma unroll
        for (int i = 0; i < 8; ++i) {
            const float xv = (float)x[i];
            a0 += xv * (float)w0[i]; a1 += xv * (float)w1[i]; a2 += xv * (float)w2[i];
        }
    }
    for (int o = 32; o > 0; o >>= 1) {
        a0 += __shfl_down(a0, o, 64); a1 += __shfl_down(a1, o, 64); a2 += __shfl_down(a2, o, 64);
    }
    const int wv = tid >> 6;
    if ((tid & 63) == 0) { rp[wv][0] = a0; rp[wv][1] = a1; rp[wv][2] = a2; }
    __syncthreads();
    if (tid < 3) {
        const float x = rp[0][tid] + rp[1][tid] + rp[2][tid] + rp[3][tid] + cst[tid];
        const int b = r & 63, ts = r >> 6;
        out[((size_t)b * TT + ts) * 3 + tid] = x;
    }
}

extern "C" void kernel_launch(void* const* d_in, const int* in_sizes, int n_in,
                              void* d_out, int out_size, void* d_ws, size_t ws_size,
                              hipStream_t stream) {
    (void)in_sizes; (void)n_in; (void)out_size;
    const float* feature = (const float*)d_in[0];
    const float* attn_Wx = (const float*)d_in[1];
    const float* attn_Wh = (const float*)d_in[2];
    const float* attn_v  = (const float*)d_in[3];
    const float* W_ih    = (const float*)d_in[4];
    const float* W_hh    = (const float*)d_in[5];
    const float* b_ih    = (const float*)d_in[6];
    const float* b_hh    = (const float*)d_in[7];
    const float* Wh_w    = (const float*)d_in[8];
    const float* Wh_b    = (const float*)d_in[9];
    const float* Wy_w    = (const float*)d_in[10];
    const float* Wu_w    = (const float*)d_in[11];
    const float* Wu_b    = (const float*)d_in[12];
    const float* iWh_w   = (const float*)d_in[13];
    const float* iWh_b   = (const float*)d_in[14];
    const float* iWc_w   = (const float*)d_in[15];
    const float* iWc_b   = (const float*)d_in[16];
    float* out = (float*)d_out;

    char* ws = (char*)d_ws;
    size_t off = 0;
    auto alloc = [&](size_t bytes) { void* p = ws + off; off += (bytes + 255) & ~(size_t)255; return p; };
    _Float16* Wih16 = (_Float16*)alloc((size_t)NG * RR * 2);
    _Float16* Whh16 = (_Float16*)alloc((size_t)NG * HH * 2);
    _Float16* WxT16 = (_Float16*)alloc((size_t)DD * DD * 2);
    _Float16* V16   = (_Float16*)alloc((size_t)TT * NB * RR * 2);
    _Float16* H16   = (_Float16*)alloc((size_t)TT * NB * HH * 2);
    float*    hbuf  = (float*)alloc((size_t)NB * HH * 4);
    float*    cbuf  = (float*)alloc((size_t)NB * HH * 4);
    _Float16* h16   = (_Float16*)alloc((size_t)NB * HH * 2);
    float*    gpart = (float*)alloc((size_t)4 * NB * NG * 4);
    _Float16* Wyu16 = (_Float16*)alloc((size_t)3 * KT * 2);
    float*    cstb  = (float*)alloc(16);
    if (ws_size < off) return;   // refuse to scribble out of bounds

    // one-time: weight conversions + head-weight fusion (+Wx transpose) + init
    k_conv<<<(NG * RR / 4 + 255) / 256, 256, 0, stream>>>(W_ih, Wih16, NG * RR);
    k_conv<<<(NG * HH / 4 + 255) / 256, 256, 0, stream>>>(W_hh, Whh16, NG * HH);
    k_wfuse<<<CHT + 2, 256, 0, stream>>>(Wy_w, Wh_w, Wu_w, Wh_b, Wu_b, Wyu16, cstb,
                                         attn_Wx, WxT16);
    k_init<<<64, 256, 0, stream>>>(feature, iWh_w, iWh_b, iWc_w, iWc_b, hbuf, cbuf, h16);

    // attention for t=0 from h0
    k_step<<<64, 512, 0, stream>>>(0, 0, gpart, b_ih, b_hh, cbuf, h16, H16, hbuf,
                                   feature, WxT16, attn_Wh, attn_v, V16);
    for (int t = 0; t < TT; ++t) {
        const _Float16* Vt = V16 + (size_t)t * NB * RR;
        k_gemm<64, 4><<<256, 128, 0, stream>>>(Vt, h16, Wih16, Whh16,
                                               gpart, NG, (size_t)NB * NG);
        k_step<<<64, 512, 0, stream>>>(t + 1, 1, gpart, b_ih, b_hh, cbuf, h16, H16, hbuf,
                                       feature, WxT16, attn_Wh, attn_v, V16);
    }

    k_final2<<<1280, 256, 0, stream>>>(V16, H16, Wyu16, cstb, out);
}